// Round 1
// baseline (220.663 us; speedup 1.0000x reference)
//
#include <hip/hip_runtime.h>

#define NN 50000
#define NE 250000
#define KTVC 4224   // 4*32*32 ktv + 4*32 ksum
#define NBK 512     // ktv partial blocks

__device__ __forceinline__ float lrelu(float x) { return x > 0.f ? x : 0.01f * x; }

// ---------------- kernel 1: histograms ----------------
__global__ __launch_bounds__(256) void k_hist(const int* __restrict__ src,
                                              const int* __restrict__ dst,
                                              int* __restrict__ cnt_src,
                                              int* __restrict__ cnt_dst) {
    int e = blockIdx.x * 256 + threadIdx.x;
    if (e < NE) {
        atomicAdd(&cnt_src[src[e]], 1);
        atomicAdd(&cnt_dst[dst[e]], 1);
    }
}

// ---------------- kernel 2: fc + LN + leaky -> residual[N][36], node33[N][36] ----------------
// 256 threads: tid = j*8 + ns*4 + ic ; block handles 64 nodes (4 tiles of 16)
__global__ __launch_bounds__(256) void k_fc(const float* __restrict__ h,
                                            const float* __restrict__ Wfc,
                                            const float* __restrict__ bfc,
                                            const float* __restrict__ g1,
                                            const float* __restrict__ b1,
                                            float* __restrict__ resid,
                                            float* __restrict__ node33) {
    __shared__ float h_lds[16][4][36];
    __shared__ float s_lds[16][33];
    __shared__ float bias_lds[32];
    const int tid = threadIdx.x;
    const int ic = tid & 3, ns = (tid >> 2) & 1, j = tid >> 3;
    float w[32];
#pragma unroll
    for (int i = 0; i < 32; ++i) w[i] = Wfc[(1 + ic * 32 + i) * 32 + j];
    if (tid < 32) bias_lds[tid] = Wfc[tid] + bfc[tid];
    const float g1v = g1[tid & 31], b1v = b1[tid & 31];

    const int base = blockIdx.x * 64;
    for (int tile = 0; tile < 4; ++tile) {
        const int tbase = base + tile * 16;
        __syncthreads();
        // stage h: 16 nodes x 128 floats, coalesced
#pragma unroll
        for (int r = 0; r < 2; ++r) {
            int f4 = tid * 2 + r;          // 0..511
            int n = f4 >> 5, i4 = f4 & 31;
            int gn = tbase + n;
            float4 v = make_float4(0.f, 0.f, 0.f, 0.f);
            if (gn < NN) v = ((const float4*)(h + (size_t)gn * 128))[i4];
            int ii = i4 * 4;
            *(float4*)&h_lds[n][ii >> 5][ii & 31] = v;
        }
        __syncthreads();
        for (int it = 0; it < 8; ++it) {
            const int nt = it * 2 + ns;
            float acc = 0.f;
#pragma unroll
            for (int r = 0; r < 8; ++r) {
                float4 hv = *(const float4*)&h_lds[nt][ic][r * 4];
                acc += hv.x * w[r * 4 + 0] + hv.y * w[r * 4 + 1] +
                       hv.z * w[r * 4 + 2] + hv.w * w[r * 4 + 3];
            }
            acc += __shfl_xor(acc, 1);
            acc += __shfl_xor(acc, 2);
            if (ic == 0) s_lds[nt][j] = acc + bias_lds[j];
        }
        __syncthreads();
#pragma unroll
        for (int rep = 0; rep < 2; ++rep) {
            const int nl = rep * 8 + (tid >> 5);
            const int jj = tid & 31;
            const int gn = tbase + nl;
            float s = s_lds[nl][jj];
            float sm = s, sq = s * s;
#pragma unroll
            for (int msk = 16; msk >= 1; msk >>= 1) {
                sm += __shfl_xor(sm, msk);
                sq += __shfl_xor(sq, msk);
            }
            float mean = sm * (1.f / 32.f);
            float var = fmaxf(sq * (1.f / 32.f) - mean * mean, 0.f);
            float rstd = rsqrtf(var + 1e-5f);
            float ln = (s - mean) * rstd * g1v + b1v;
            float lr = lrelu(ln);
            float l2 = lr * lr;
#pragma unroll
            for (int msk = 16; msk >= 1; msk >>= 1) l2 += __shfl_xor(l2, msk);
            if (gn < NN) {
                resid[(size_t)gn * 36 + 1 + jj] = s;
                node33[(size_t)gn * 36 + 1 + jj] = lr;
                if (jj == 0) {
                    resid[(size_t)gn * 36] = sqrtf(sq + 1.f);
                    node33[(size_t)gn * 36] = sqrtf(l2 + 1.f);
                }
            }
        }
    }
}

// ---------------- kernel 3: qkv + phi + ktv partials ----------------
// 384 threads: tid = m*128 + hh*32 + j ; m in {q,k,v}
__global__ __launch_bounds__(384) void k_qkv(const float* __restrict__ node33,
                                             const float* __restrict__ Wq, const float* __restrict__ bq,
                                             const float* __restrict__ Wk, const float* __restrict__ bk,
                                             const float* __restrict__ Wv, const float* __restrict__ bv,
                                             const float* __restrict__ nscale,
                                             const int* __restrict__ cnt_src,
                                             float* __restrict__ phiqT,
                                             float* __restrict__ partial) {
    __shared__ float node_lds[32][36];
    __shared__ float pk_lds[32][128];
    __shared__ float pv_lds[32][128];
    __shared__ float wc_lds[32];
    const int tid = threadIdx.x;
    const int m = tid >> 7, hh = (tid >> 5) & 3, j = tid & 31;
    const float* Wm = (m == 0) ? Wq : (m == 1 ? Wk : Wv);
    const float* bm = (m == 0) ? bq : (m == 1 ? bk : bv);
    float w[33];
#pragma unroll
    for (int t = 0; t < 33; ++t) w[t] = Wm[(hh * 33 + t) * 32 + j];
    const float bias = bm[hh * 32 + j];
    const float inv_scale = 1.f / fabsf(nscale[0]);
    const int d0 = m * 12;
    const int nd = (m == 2) ? 2 : 3;
    float a[12];
#pragma unroll
    for (int r = 0; r < 12; ++r) a[r] = 0.f;
    float ak = 0.f;

    const int ntiles = (NN + 31) / 32;
    for (int tile = blockIdx.x; tile < ntiles; tile += NBK) {
        const int base = tile * 32;
        const int nn = min(32, NN - base);
        __syncthreads();
        for (int f = tid; f < 32 * 9; f += 384) {
            int nl = f / 9, c4 = f % 9;
            float4 v = make_float4(0.f, 0.f, 0.f, 0.f);
            if (nl < nn) v = ((const float4*)(node33 + (size_t)(base + nl) * 36))[c4];
            *(float4*)&node_lds[nl][c4 * 4] = v;
        }
        if (tid < nn) wc_lds[tid] = (float)cnt_src[base + tid];
        __syncthreads();
        for (int nl = 0; nl < nn; ++nl) {
            float acc = bias;
#pragma unroll
            for (int r = 0; r < 8; ++r) {
                float4 nv = *(const float4*)&node_lds[nl][r * 4];
                acc += nv.x * w[r * 4 + 0] + nv.y * w[r * 4 + 1] +
                       nv.z * w[r * 4 + 2] + nv.w * w[r * 4 + 3];
            }
            acc += node_lds[nl][32] * w[32];
            float x = (lrelu(acc) + 1e-6f) * inv_scale;
            float outv;
            if (m < 2) {
                float x3 = x * x * x;
                float s2 = x * x, s6 = x3 * x3;
#pragma unroll
                for (int msk = 16; msk >= 1; msk >>= 1) {
                    s2 += __shfl_xor(s2, msk);
                    s6 += __shfl_xor(s6, msk);
                }
                outv = sqrtf(s2) / sqrtf(s6) * x3;
            } else {
                outv = x;
            }
            if (m == 0)      phiqT[(size_t)(hh * 32 + j) * NN + (base + nl)] = outv;
            else if (m == 1) pk_lds[nl][hh * 32 + j] = outv;
            else             pv_lds[nl][hh * 32 + j] = outv;
        }
        __syncthreads();
        for (int nl = 0; nl < nn; ++nl) {
            const float wc = wc_lds[nl];
            const float pk = pk_lds[nl][hh * 32 + j];
            const float pkw = pk * wc;
            if (m == 0) ak += pkw;
#pragma unroll
            for (int r3 = 0; r3 < 3; ++r3) {
                if (r3 < nd) {
                    float4 pv = *(const float4*)&pv_lds[nl][hh * 32 + d0 + r3 * 4];
                    a[r3 * 4 + 0] += pkw * pv.x;
                    a[r3 * 4 + 1] += pkw * pv.y;
                    a[r3 * 4 + 2] += pkw * pv.z;
                    a[r3 * 4 + 3] += pkw * pv.w;
                }
            }
        }
    }
    float* pb = partial + (size_t)blockIdx.x * KTVC;
    const int cnt = (m == 2) ? 8 : 12;
#pragma unroll
    for (int r = 0; r < 12; ++r)
        if (r < cnt) pb[hh * 1024 + j * 32 + d0 + r] = a[r];
    if (m == 0) pb[4096 + hh * 32 + j] = ak;
}

// ---------------- kernel 4: reduce ktv partials ----------------
__global__ __launch_bounds__(256) void k_red(const float* __restrict__ partial,
                                             float* __restrict__ ktvf) {
    int c = blockIdx.x * 256 + threadIdx.x;
    if (c >= KTVC) return;
    float s0 = 0.f, s1 = 0.f, s2 = 0.f, s3 = 0.f;
    for (int b = 0; b < NBK; b += 4) {
        s0 += partial[(size_t)(b + 0) * KTVC + c];
        s1 += partial[(size_t)(b + 1) * KTVC + c];
        s2 += partial[(size_t)(b + 2) * KTVC + c];
        s3 += partial[(size_t)(b + 3) * KTVC + c];
    }
    ktvf[c] = (s0 + s1) + (s2 + s3);
}

// ---------------- kernel 5: attention + edge_out + midpoint + LN2 -> out ----------------
__global__ __launch_bounds__(128) void k_final(const float* __restrict__ phiqT,
                                               const float* __restrict__ ktvf,
                                               const float* __restrict__ Who,
                                               const float* __restrict__ bho,
                                               const float* __restrict__ g2,
                                               const float* __restrict__ b2,
                                               const int* __restrict__ cnt_dst,
                                               const float* __restrict__ resid,
                                               float* __restrict__ out) {
    __shared__ float ktv_lds[KTVC];
    __shared__ float who_lds[33 * 32];
    __shared__ float bho_lds[32], g2_lds[32], b2_lds[32];
    __shared__ float otile[128 * 33];
    const int tid = threadIdx.x;
    for (int f = tid; f < KTVC; f += 128) ktv_lds[f] = ktvf[f];
    for (int f = tid; f < 33 * 32; f += 128) who_lds[f] = Who[f];
    if (tid < 32) { bho_lds[tid] = bho[tid]; g2_lds[tid] = g2[tid]; b2_lds[tid] = b2[tid]; }
    __syncthreads();
    const int n = blockIdx.x * 128 + tid;
    const int nc = (n < NN) ? n : NN - 1;

    float attn[32];
#pragma unroll
    for (int d = 0; d < 32; ++d) attn[d] = 0.f;
    for (int hh = 0; hh < 4; ++hh) {
        float pq[32];
#pragma unroll
        for (int c = 0; c < 32; ++c) pq[c] = phiqT[(size_t)(hh * 32 + c) * NN + nc];
        float den = 0.f;
#pragma unroll
        for (int c = 0; c < 32; ++c) den += pq[c] * ktv_lds[4096 + hh * 32 + c];
        float num[32];
#pragma unroll
        for (int d = 0; d < 32; ++d) num[d] = 0.f;
#pragma unroll
        for (int t = 0; t < 32; ++t) {
            const float f = pq[t];
            const float* kr = &ktv_lds[hh * 1024 + t * 32];
#pragma unroll
            for (int d4 = 0; d4 < 8; ++d4) {
                float4 kv = *(const float4*)&kr[d4 * 4];
                num[d4 * 4 + 0] += f * kv.x;
                num[d4 * 4 + 1] += f * kv.y;
                num[d4 * 4 + 2] += f * kv.z;
                num[d4 * 4 + 3] += f * kv.w;
            }
        }
        const float rd = 0.25f / (den + 1e-6f);
#pragma unroll
        for (int d = 0; d < 32; ++d) attn[d] += num[d] * rd;
    }
    float a2 = 0.f;
#pragma unroll
    for (int d = 0; d < 32; ++d) a2 += attn[d] * attn[d];
    const float tc = sqrtf(a2 + 1.f);
    float eo[32];
#pragma unroll
    for (int jj = 0; jj < 32; ++jj) eo[jj] = bho_lds[jj] + tc * who_lds[jj];
#pragma unroll
    for (int d = 0; d < 32; ++d) {
        const float f = attn[d];
        const float* wr = &who_lds[(1 + d) * 32];
#pragma unroll
        for (int j4 = 0; j4 < 8; ++j4) {
            float4 wv = *(const float4*)&wr[j4 * 4];
            eo[j4 * 4 + 0] += f * wv.x;
            eo[j4 * 4 + 1] += f * wv.y;
            eo[j4 * 4 + 2] += f * wv.z;
            eo[j4 * 4 + 3] += f * wv.w;
        }
    }
    float e2 = 0.f;
#pragma unroll
    for (int jj = 0; jj < 32; ++jj) e2 += eo[jj] * eo[jj];
    const float te = sqrtf(e2 + 1.f);
    const float sc = (cnt_dst[nc] > 0) ? 1.f : 0.f;
    const float* rr = resid + (size_t)nc * 36;
    float av0 = 0.5f * (sc * te + rr[0]);
    float avs[32];
    float inner = -av0 * av0;
#pragma unroll
    for (int jj = 0; jj < 32; ++jj) {
        avs[jj] = 0.5f * (sc * eo[jj] + rr[1 + jj]);
        inner += avs[jj] * avs[jj];
    }
    const float rdn = 1.f / sqrtf(fmaxf(fabsf(inner), 1e-6f));
    float mean = 0.f;
#pragma unroll
    for (int jj = 0; jj < 32; ++jj) { avs[jj] *= rdn; mean += avs[jj]; }
    mean *= (1.f / 32.f);
    float var = 0.f;
#pragma unroll
    for (int jj = 0; jj < 32; ++jj) { float dd = avs[jj] - mean; var += dd * dd; }
    var *= (1.f / 32.f);
    const float rstd = rsqrtf(var + 1e-5f);
    float l2 = 0.f;
#pragma unroll
    for (int jj = 0; jj < 32; ++jj) {
        float ln = (avs[jj] - mean) * rstd * g2_lds[jj] + b2_lds[jj];
        otile[tid * 33 + 1 + jj] = ln;
        l2 += ln * ln;
    }
    otile[tid * 33] = sqrtf(l2 + 1.f);
    __syncthreads();
    const size_t gb = (size_t)blockIdx.x * 128 * 33;
#pragma unroll
    for (int r = 0; r < 33; ++r) {
        size_t f = (size_t)r * 128 + tid;
        if (gb + f < (size_t)NN * 33) out[gb + f] = otile[f];
    }
}

extern "C" void kernel_launch(void* const* d_in, const int* in_sizes, int n_in,
                              void* d_out, int out_size, void* d_ws, size_t ws_size,
                              hipStream_t stream) {
    const float* h   = (const float*)d_in[0];
    const int* src   = (const int*)d_in[1];
    const int* dst   = (const int*)d_in[2];
    const float* Wfc = (const float*)d_in[3];
    const float* bfc = (const float*)d_in[4];
    const float* g1  = (const float*)d_in[5];
    const float* b1  = (const float*)d_in[6];
    const float* Wq  = (const float*)d_in[7];
    const float* bq  = (const float*)d_in[8];
    const float* Wk  = (const float*)d_in[9];
    const float* bk  = (const float*)d_in[10];
    const float* Wv  = (const float*)d_in[11];
    const float* bv  = (const float*)d_in[12];
    const float* Who = (const float*)d_in[13];
    const float* bho = (const float*)d_in[14];
    const float* g2  = (const float*)d_in[15];
    const float* b2  = (const float*)d_in[16];
    const float* nsc = (const float*)d_in[17];
    float* out = (float*)d_out;
    char* ws = (char*)d_ws;

    int* cnt_src  = (int*)(ws + 0);          //  200000 B
    int* cnt_dst  = (int*)(ws + 200000);     //  200000 B
    float* resid  = (float*)(ws + 400000);   //  7.2 MB  [N][36]
    float* node33 = (float*)(ws + 7600000);  //  7.2 MB  [N][36]
    float* phiqT  = (float*)(ws + 14800000); // 25.6 MB  [128][N]
    float* part   = (float*)(ws + 40400000); //  8.65 MB [512][4224]
    float* ktvf   = (float*)(ws + 49051776); //  16.9 KB

    hipMemsetAsync(ws, 0, 400000, stream);
    hipLaunchKernelGGL(k_hist, dim3((NE + 255) / 256), dim3(256), 0, stream,
                       src, dst, cnt_src, cnt_dst);
    hipLaunchKernelGGL(k_fc, dim3((NN + 63) / 64), dim3(256), 0, stream,
                       h, Wfc, bfc, g1, b1, resid, node33);
    hipLaunchKernelGGL(k_qkv, dim3(NBK), dim3(384), 0, stream,
                       node33, Wq, bq, Wk, bk, Wv, bv, nsc, cnt_src, phiqT, part);
    hipLaunchKernelGGL(k_red, dim3((KTVC + 255) / 256), dim3(256), 0, stream,
                       part, ktvf);
    hipLaunchKernelGGL(k_final, dim3((NN + 127) / 128), dim3(128), 0, stream,
                       phiqT, ktvf, Who, bho, g2, b2, cnt_dst, resid, out);
}

// Round 2
// 171.998 us; speedup vs baseline: 1.2829x; 1.2829x over previous
//
#include <hip/hip_runtime.h>

#define NN 50000
#define NE 250000
#define KTVC 4224   // 4*32*32 ktv + 4*32 ksum

__device__ __forceinline__ float lrelu(float x) { return x > 0.f ? x : 0.01f * x; }

// ---------------- kernel 1: histograms ----------------
__global__ __launch_bounds__(256) void k_hist(const int* __restrict__ src,
                                              const int* __restrict__ dst,
                                              int* __restrict__ cnt_src,
                                              int* __restrict__ cnt_dst) {
    int e = blockIdx.x * 256 + threadIdx.x;
    if (e < NE) {
        atomicAdd(&cnt_src[src[e]], 1);
        atomicAdd(&cnt_dst[dst[e]], 1);
    }
}

// ---------------- kernel 2: fc + LN + leaky ----------------
// 512 threads = 4 col-quarters x 128 nodes. lane-per-node, scalar weights.
__global__ __launch_bounds__(512) void k_fc(const float* __restrict__ h,
                                            const float* __restrict__ Wfc,
                                            const float* __restrict__ bfc,
                                            const float* __restrict__ g1,
                                            const float* __restrict__ b1,
                                            float* __restrict__ resid,
                                            float* __restrict__ node33T) {
    __shared__ float hch[128][33];
    __shared__ float stat_t[8][128];   // (q*2+k) major: sum_s, sum_s2 partials
    __shared__ float stat2_t[4][128];  // sum lr^2 partials
    const int tid = threadIdx.x;
    const int q = __builtin_amdgcn_readfirstlane((threadIdx.x >> 7) & 3);
    const int nl = tid & 127;
    const int base = blockIdx.x * 128;
    const int n = base + nl;

    float acc[8];
#pragma unroll
    for (int jj = 0; jj < 8; ++jj) acc[jj] = Wfc[q * 8 + jj] + bfc[q * 8 + jj];

    for (int c = 0; c < 4; ++c) {
        __syncthreads();
#pragma unroll
        for (int r = 0; r < 8; ++r) {
            int idx = r * 512 + tid;
            int sn = idx >> 5, t = idx & 31;
            int gn = base + sn;
            hch[sn][t] = h[(size_t)((gn < NN) ? gn : 0) * 128 + c * 32 + t];
        }
        __syncthreads();
        for (int i = 0; i < 32; ++i) {
            float hv = hch[nl][i];
            const float* wr = Wfc + (size_t)(1 + c * 32 + i) * 32 + q * 8;
#pragma unroll
            for (int jj = 0; jj < 8; ++jj) acc[jj] = fmaf(hv, wr[jj], acc[jj]);
        }
    }
    // stats across the 4 quarters
    float ps = 0.f, pq2 = 0.f;
#pragma unroll
    for (int jj = 0; jj < 8; ++jj) { ps += acc[jj]; pq2 += acc[jj] * acc[jj]; }
    stat_t[q * 2 + 0][nl] = ps;
    stat_t[q * 2 + 1][nl] = pq2;
    __syncthreads();
    float sm = stat_t[0][nl] + stat_t[2][nl] + stat_t[4][nl] + stat_t[6][nl];
    float sq = stat_t[1][nl] + stat_t[3][nl] + stat_t[5][nl] + stat_t[7][nl];
    float mean = sm * (1.f / 32.f);
    float var = fmaxf(sq * (1.f / 32.f) - mean * mean, 0.f);
    float rstd = rsqrtf(var + 1e-5f);
    float lr[8];
    float pl2 = 0.f;
#pragma unroll
    for (int jj = 0; jj < 8; ++jj) {
        int j = q * 8 + jj;
        float ln = (acc[jj] - mean) * rstd * g1[j] + b1[j];
        lr[jj] = lrelu(ln);
        pl2 += lr[jj] * lr[jj];
    }
    stat2_t[q][nl] = pl2;
    __syncthreads();
    float l2 = stat2_t[0][nl] + stat2_t[1][nl] + stat2_t[2][nl] + stat2_t[3][nl];
    if (n < NN) {
        float* rrow = resid + (size_t)n * 36;
#pragma unroll
        for (int jj = 0; jj < 8; ++jj) rrow[1 + q * 8 + jj] = acc[jj];
#pragma unroll
        for (int jj = 0; jj < 8; ++jj) node33T[(size_t)(1 + q * 8 + jj) * NN + n] = lr[jj];
        if (q == 0) {
            rrow[0] = sqrtf(sq + 1.f);
            node33T[n] = sqrtf(l2 + 1.f);
        }
    }
}

// ---------------- kernel 3: k/v matvec + phi + per-wave ktv partials ----------------
// 512 threads = 8 waves = (m in {k,v}) x (4 heads); lanes = 64 nodes of this block.
__global__ __launch_bounds__(512) void k_qkv(const float* __restrict__ node33T,
                                             const float* __restrict__ Wk, const float* __restrict__ bk,
                                             const float* __restrict__ Wv, const float* __restrict__ bv,
                                             const float* __restrict__ nscale,
                                             const int* __restrict__ cnt_src,
                                             float* __restrict__ partial) {
    __shared__ float nlds[64][37];
    __shared__ float pk[4][64][33];
    __shared__ float pv[4][64][33];
    const int tid = threadIdx.x;
    const int w_u = __builtin_amdgcn_readfirstlane(tid >> 6);
    const int m_u = w_u >> 2;      // 0 = k, 1 = v
    const int h_u = w_u & 3;
    const int lane = tid & 63;
    const int base = blockIdx.x * 64;
    const int n = base + lane;
    const float inv = 1.f / fabsf(nscale[0]);

    // stage node vectors [64][33] from column-major global
#pragma unroll
    for (int r = 0; r < 5; ++r) {
        int idx = r * 512 + tid;
        if (idx < 2112) {
            int c = idx >> 6, sn = idx & 63;
            int gn = base + sn;
            nlds[sn][c] = node33T[(size_t)c * NN + ((gn < NN) ? gn : 0)];
        }
    }
    __syncthreads();

    const float* W = ((m_u == 0) ? Wk : Wv) + (size_t)h_u * 33 * 32;
    const float* bb = ((m_u == 0) ? bk : bv) + h_u * 32;
    float acc[32];
#pragma unroll
    for (int j = 0; j < 32; ++j) acc[j] = bb[j];
    for (int i = 0; i < 33; ++i) {
        float hv = nlds[lane][i];
        const float* wr = W + (size_t)i * 32;
#pragma unroll
        for (int j = 0; j < 32; ++j) acc[j] = fmaf(hv, wr[j], acc[j]);
    }

    if (m_u == 0) {
        const float wc = (n < NN) ? (float)cnt_src[n] : 0.f;
        float s2 = 0.f, s6 = 0.f;
#pragma unroll
        for (int j = 0; j < 32; ++j) {
            float x = (lrelu(acc[j]) + 1e-6f) * inv;
            s2 += x * x;
            float x3 = x * x * x;
            s6 += x3 * x3;
            acc[j] = x3;
        }
        const float factor = sqrtf(s2) / sqrtf(s6) * wc;
#pragma unroll
        for (int j = 0; j < 32; ++j) pk[h_u][lane][j] = factor * acc[j];
    } else {
#pragma unroll
        for (int j = 0; j < 32; ++j) pv[h_u][lane][j] = (lrelu(acc[j]) + 1e-6f) * inv;
    }
    __syncthreads();

    // ktv: k-waves take nodes 0..31, v-waves take 32..63 (head h_u).
    const int mm4 = lane >> 3, d4 = lane & 7;
    float facc[16];
#pragma unroll
    for (int t = 0; t < 16; ++t) facc[t] = 0.f;
    float ks[4] = {0.f, 0.f, 0.f, 0.f};
#pragma unroll 2
    for (int n0 = 0; n0 < 32; ++n0) {
        const int nn = m_u * 32 + n0;
        float pkv[4], pvv[4];
#pragma unroll
        for (int i = 0; i < 4; ++i) pkv[i] = pk[h_u][nn][mm4 * 4 + i];
#pragma unroll
        for (int i = 0; i < 4; ++i) pvv[i] = pv[h_u][nn][d4 * 4 + i];
#pragma unroll
        for (int i = 0; i < 4; ++i)
#pragma unroll
            for (int jj = 0; jj < 4; ++jj) facc[i * 4 + jj] = fmaf(pkv[i], pvv[jj], facc[i * 4 + jj]);
        if (d4 == 0) {
#pragma unroll
            for (int i = 0; i < 4; ++i) ks[i] += pkv[i];
        }
    }
    float* pb = partial + (size_t)(blockIdx.x * 2 + m_u) * KTVC;
#pragma unroll
    for (int i = 0; i < 4; ++i)
#pragma unroll
        for (int jj = 0; jj < 4; ++jj)
            pb[h_u * 1024 + (mm4 * 4 + i) * 32 + d4 * 4 + jj] = facc[i * 4 + jj];
    if (d4 == 0) {
#pragma unroll
        for (int i = 0; i < 4; ++i) pb[4096 + h_u * 32 + mm4 * 4 + i] = ks[i];
    }
}

// ---------------- kernel 4: reduce partials (2 levels) ----------------
__global__ __launch_bounds__(256) void k_red1(const float* __restrict__ partial,
                                              float* __restrict__ tmp) {
    int gid = blockIdx.x * 256 + threadIdx.x;
    if (gid >= 4 * KTVC) return;
    int g = gid / KTVC, c = gid % KTVC;
    float s = 0.f;
    for (int r = 0; r < 391; ++r) s += partial[(size_t)(g * 391 + r) * KTVC + c];
    tmp[gid] = s;
}
__global__ __launch_bounds__(256) void k_red2(const float* __restrict__ tmp,
                                              float* __restrict__ ktvf) {
    int c = blockIdx.x * 256 + threadIdx.x;
    if (c < KTVC)
        ktvf[c] = (tmp[c] + tmp[KTVC + c]) + (tmp[2 * KTVC + c] + tmp[3 * KTVC + c]);
}

// ---------------- kernel 5: q + phi_q + attention + edge_out + midpoint + LN2 ----------------
// 256 threads = 4 waves (one head each) x 64 nodes.
__global__ __launch_bounds__(256) void k_final(const float* __restrict__ node33T,
                                               const float* __restrict__ Wq, const float* __restrict__ bq,
                                               const float* __restrict__ nscale,
                                               const float* __restrict__ ktvf,
                                               const float* __restrict__ Who,
                                               const float* __restrict__ bho,
                                               const float* __restrict__ g2,
                                               const float* __restrict__ b2,
                                               const int* __restrict__ cnt_dst,
                                               const float* __restrict__ resid,
                                               float* __restrict__ out) {
    __shared__ float nlds[64][37];
    __shared__ float att[4][64][33];
    __shared__ float who_lds[33 * 32];
    __shared__ float g2l[32], b2l[32], bhol[32];
    const int tid = threadIdx.x;
    const int h_u = __builtin_amdgcn_readfirstlane(tid >> 6);
    const int lane = tid & 63;
    const int base = blockIdx.x * 64;
    const float inv = 1.f / fabsf(nscale[0]);

#pragma unroll
    for (int r = 0; r < 9; ++r) {
        int idx = r * 256 + tid;
        if (idx < 2112) {
            int c = idx >> 6, sn = idx & 63;
            int gn = base + sn;
            nlds[sn][c] = node33T[(size_t)c * NN + ((gn < NN) ? gn : 0)];
        }
    }
    for (int f = tid; f < 33 * 32; f += 256) who_lds[f] = Who[f];
    if (tid < 32) { g2l[tid] = g2[tid]; b2l[tid] = b2[tid]; bhol[tid] = bho[tid]; }
    __syncthreads();

    // ---- phase A: per (node, head): q matvec + phi_q + num/den ----
    {
        float acc[32];
#pragma unroll
        for (int j = 0; j < 32; ++j) acc[j] = bq[h_u * 32 + j];
        const float* W = Wq + (size_t)h_u * 33 * 32;
        for (int i = 0; i < 33; ++i) {
            float hv = nlds[lane][i];
            const float* wr = W + (size_t)i * 32;
#pragma unroll
            for (int j = 0; j < 32; ++j) acc[j] = fmaf(hv, wr[j], acc[j]);
        }
        float s2 = 0.f, s6 = 0.f;
#pragma unroll
        for (int j = 0; j < 32; ++j) {
            float x = (lrelu(acc[j]) + 1e-6f) * inv;
            s2 += x * x;
            float x3 = x * x * x;
            s6 += x3 * x3;
            acc[j] = x3;
        }
        const float factor = sqrtf(s2) / sqrtf(s6);
        const float* ksum = ktvf + 4096 + h_u * 32;
        float den = 0.f;
#pragma unroll
        for (int j = 0; j < 32; ++j) { acc[j] *= factor; den += acc[j] * ksum[j]; }
        const float rd = 0.25f / (den + 1e-6f);
        float num[32];
#pragma unroll
        for (int d = 0; d < 32; ++d) num[d] = 0.f;
        const float* kt = ktvf + h_u * 1024;
#pragma unroll 2
        for (int t = 0; t < 32; ++t) {
            const float f = acc[t];
            const float* kr = kt + t * 32;
#pragma unroll
            for (int d = 0; d < 32; ++d) num[d] = fmaf(f, kr[d], num[d]);
        }
#pragma unroll
        for (int d = 0; d < 32; ++d) att[h_u][lane][d] = num[d] * rd;
    }
    __syncthreads();

    // ---- phase B: per node (4 threads each, jq = quarter of output cols) ----
    const int nl2 = tid >> 2, jq = tid & 3;
    const int n2 = base + nl2;
    const int nc = (n2 < NN) ? n2 : NN - 1;
    float attn[32];
#pragma unroll
    for (int d = 0; d < 32; ++d)
        attn[d] = ((att[0][nl2][d] + att[1][nl2][d]) + (att[2][nl2][d] + att[3][nl2][d]));
    float a2 = 0.f;
#pragma unroll
    for (int d = 0; d < 32; ++d) a2 += attn[d] * attn[d];
    const float tc = sqrtf(a2 + 1.f);
    float eo[8];
#pragma unroll
    for (int jj = 0; jj < 8; ++jj) {
        int j = jq * 8 + jj;
        eo[jj] = bhol[j] + tc * who_lds[j];
    }
#pragma unroll
    for (int d = 0; d < 32; ++d) {
        const float f = attn[d];
        const float* wr = &who_lds[(1 + d) * 32 + jq * 8];
#pragma unroll
        for (int jj = 0; jj < 8; ++jj) eo[jj] = fmaf(f, wr[jj], eo[jj]);
    }
    float e2 = 0.f;
#pragma unroll
    for (int jj = 0; jj < 8; ++jj) e2 += eo[jj] * eo[jj];
    e2 += __shfl_xor(e2, 1);
    e2 += __shfl_xor(e2, 2);
    const float te = sqrtf(e2 + 1.f);
    const float sc = (cnt_dst[nc] > 0) ? 1.f : 0.f;
    const float* rr = resid + (size_t)nc * 36;
    const float av0 = 0.5f * (sc * te + rr[0]);
    float avs[8];
    float pinner = 0.f;
#pragma unroll
    for (int jj = 0; jj < 8; ++jj) {
        avs[jj] = 0.5f * (sc * eo[jj] + rr[1 + jq * 8 + jj]);
        pinner += avs[jj] * avs[jj];
    }
    pinner += __shfl_xor(pinner, 1);
    pinner += __shfl_xor(pinner, 2);
    const float inner = pinner - av0 * av0;
    const float rdn = 1.f / sqrtf(fmaxf(fabsf(inner), 1e-6f));
    float pm = 0.f;
#pragma unroll
    for (int jj = 0; jj < 8; ++jj) { avs[jj] *= rdn; pm += avs[jj]; }
    pm += __shfl_xor(pm, 1);
    pm += __shfl_xor(pm, 2);
    const float mean = pm * (1.f / 32.f);
    float pv2 = 0.f;
#pragma unroll
    for (int jj = 0; jj < 8; ++jj) { float dd = avs[jj] - mean; pv2 += dd * dd; }
    pv2 += __shfl_xor(pv2, 1);
    pv2 += __shfl_xor(pv2, 2);
    const float rstd = rsqrtf(pv2 * (1.f / 32.f) + 1e-5f);
    float ln[8];
    float pl2 = 0.f;
#pragma unroll
    for (int jj = 0; jj < 8; ++jj) {
        int j = jq * 8 + jj;
        ln[jj] = (avs[jj] - mean) * rstd * g2l[j] + b2l[j];
        pl2 += ln[jj] * ln[jj];
    }
    pl2 += __shfl_xor(pl2, 1);
    pl2 += __shfl_xor(pl2, 2);
    if (n2 < NN) {
        float* orow = out + (size_t)n2 * 33;
#pragma unroll
        for (int jj = 0; jj < 8; ++jj) orow[1 + jq * 8 + jj] = ln[jj];
        if (jq == 0) orow[0] = sqrtf(pl2 + 1.f);
    }
}

extern "C" void kernel_launch(void* const* d_in, const int* in_sizes, int n_in,
                              void* d_out, int out_size, void* d_ws, size_t ws_size,
                              hipStream_t stream) {
    const float* h   = (const float*)d_in[0];
    const int* src   = (const int*)d_in[1];
    const int* dst   = (const int*)d_in[2];
    const float* Wfc = (const float*)d_in[3];
    const float* bfc = (const float*)d_in[4];
    const float* g1  = (const float*)d_in[5];
    const float* b1  = (const float*)d_in[6];
    const float* Wq  = (const float*)d_in[7];
    const float* bq  = (const float*)d_in[8];
    const float* Wk  = (const float*)d_in[9];
    const float* bk  = (const float*)d_in[10];
    const float* Wv  = (const float*)d_in[11];
    const float* bv  = (const float*)d_in[12];
    const float* Who = (const float*)d_in[13];
    const float* bho = (const float*)d_in[14];
    const float* g2  = (const float*)d_in[15];
    const float* b2  = (const float*)d_in[16];
    const float* nsc = (const float*)d_in[17];
    float* out = (float*)d_out;
    char* ws = (char*)d_ws;

    int* cnt_src   = (int*)(ws + 0);           //  200,000 B
    int* cnt_dst   = (int*)(ws + 200000);      //  200,000 B
    float* resid   = (float*)(ws + 400000);    //  7.2 MB  [NN][36]
    float* node33T = (float*)(ws + 7600000);   //  6.6 MB  [33][NN]
    float* part    = (float*)(ws + 14200000);  // 26.4 MB  [1564][4224]
    float* tmp     = (float*)(ws + 40625344);  // 67.6 KB  [4][4224]
    float* ktvf    = (float*)(ws + 40692928);  // 16.9 KB

    hipMemsetAsync(ws, 0, 400000, stream);
    hipLaunchKernelGGL(k_hist, dim3((NE + 255) / 256), dim3(256), 0, stream,
                       src, dst, cnt_src, cnt_dst);
    hipLaunchKernelGGL(k_fc, dim3((NN + 127) / 128), dim3(512), 0, stream,
                       h, Wfc, bfc, g1, b1, resid, node33T);
    hipLaunchKernelGGL(k_qkv, dim3((NN + 63) / 64), dim3(512), 0, stream,
                       node33T, Wk, bk, Wv, bv, nsc, cnt_src, part);
    hipLaunchKernelGGL(k_red1, dim3((4 * KTVC + 255) / 256), dim3(256), 0, stream,
                       part, tmp);
    hipLaunchKernelGGL(k_red2, dim3((KTVC + 255) / 256), dim3(256), 0, stream,
                       tmp, ktvf);
    hipLaunchKernelGGL(k_final, dim3((NN + 63) / 64), dim3(256), 0, stream,
                       node33T, Wq, bq, nsc, ktvf, Who, bho, g2, b2, cnt_dst, resid, out);
}

// Round 3
// 144.120 us; speedup vs baseline: 1.5311x; 1.1934x over previous
//
#include <hip/hip_runtime.h>

#define NN 50000
#define NE 250000
#define KTVC 4224        // 4*32*32 ktv + 4*32 ksum
#define QKV_BLOCKS 256   // grid-stride blocks for k_qkv
#define PART_ROWS (QKV_BLOCKS * 2)

__device__ __forceinline__ float lrelu(float x) { return x > 0.f ? x : 0.01f * x; }

// ---------------- kernel 1: histograms ----------------
__global__ __launch_bounds__(256) void k_hist(const int* __restrict__ src,
                                              const int* __restrict__ dst,
                                              int* __restrict__ cnt_src,
                                              int* __restrict__ cnt_dst) {
    int e = blockIdx.x * 256 + threadIdx.x;
    if (e < NE) {
        atomicAdd(&cnt_src[src[e]], 1);
        atomicAdd(&cnt_dst[dst[e]], 1);
    }
}

// ---------------- kernel 2: fc + LN + leaky ----------------
// 512 threads = 4 col-quarters x 128 nodes. lane-per-node, scalar weights.
__global__ __launch_bounds__(512) void k_fc(const float* __restrict__ h,
                                            const float* __restrict__ Wfc,
                                            const float* __restrict__ bfc,
                                            const float* __restrict__ g1,
                                            const float* __restrict__ b1,
                                            float* __restrict__ resid,
                                            float* __restrict__ node33T) {
    __shared__ float hch[128][33];
    __shared__ float stat_t[8][128];   // (q*2+k) major: sum_s, sum_s2 partials
    __shared__ float stat2_t[4][128];  // sum lr^2 partials
    const int tid = threadIdx.x;
    const int q = __builtin_amdgcn_readfirstlane((threadIdx.x >> 7) & 3);
    const int nl = tid & 127;
    const int base = blockIdx.x * 128;
    const int n = base + nl;

    float acc[8];
#pragma unroll
    for (int jj = 0; jj < 8; ++jj) acc[jj] = Wfc[q * 8 + jj] + bfc[q * 8 + jj];

    for (int c = 0; c < 4; ++c) {
        __syncthreads();
#pragma unroll
        for (int r = 0; r < 8; ++r) {
            int idx = r * 512 + tid;
            int sn = idx >> 5, t = idx & 31;
            int gn = base + sn;
            hch[sn][t] = h[(size_t)((gn < NN) ? gn : 0) * 128 + c * 32 + t];
        }
        __syncthreads();
        for (int i = 0; i < 32; ++i) {
            float hv = hch[nl][i];
            const float* wr = Wfc + (size_t)(1 + c * 32 + i) * 32 + q * 8;
#pragma unroll
            for (int jj = 0; jj < 8; ++jj) acc[jj] = fmaf(hv, wr[jj], acc[jj]);
        }
    }
    float ps = 0.f, pq2 = 0.f;
#pragma unroll
    for (int jj = 0; jj < 8; ++jj) { ps += acc[jj]; pq2 += acc[jj] * acc[jj]; }
    stat_t[q * 2 + 0][nl] = ps;
    stat_t[q * 2 + 1][nl] = pq2;
    __syncthreads();
    float sm = stat_t[0][nl] + stat_t[2][nl] + stat_t[4][nl] + stat_t[6][nl];
    float sq = stat_t[1][nl] + stat_t[3][nl] + stat_t[5][nl] + stat_t[7][nl];
    float mean = sm * (1.f / 32.f);
    float var = fmaxf(sq * (1.f / 32.f) - mean * mean, 0.f);
    float rstd = rsqrtf(var + 1e-5f);
    float lr[8];
    float pl2 = 0.f;
#pragma unroll
    for (int jj = 0; jj < 8; ++jj) {
        int j = q * 8 + jj;
        float ln = (acc[jj] - mean) * rstd * g1[j] + b1[j];
        lr[jj] = lrelu(ln);
        pl2 += lr[jj] * lr[jj];
    }
    stat2_t[q][nl] = pl2;
    __syncthreads();
    float l2 = stat2_t[0][nl] + stat2_t[1][nl] + stat2_t[2][nl] + stat2_t[3][nl];
    if (n < NN) {
        float* rrow = resid + (size_t)n * 36;
#pragma unroll
        for (int jj = 0; jj < 8; ++jj) rrow[1 + q * 8 + jj] = acc[jj];
#pragma unroll
        for (int jj = 0; jj < 8; ++jj) node33T[(size_t)(1 + q * 8 + jj) * NN + n] = lr[jj];
        if (q == 0) {
            rrow[0] = sqrtf(sq + 1.f);
            node33T[n] = sqrtf(l2 + 1.f);
        }
    }
}

// ---------------- kernel 3: k/v matvec + phi + grid-strided register ktv partials ----------------
// 512 threads = 8 waves = (m in {k,v}) x (4 heads); lanes = 64 nodes of current tile.
__global__ __launch_bounds__(512) void k_qkv(const float* __restrict__ node33T,
                                             const float* __restrict__ Wk, const float* __restrict__ bk,
                                             const float* __restrict__ Wv, const float* __restrict__ bv,
                                             const float* __restrict__ nscale,
                                             const int* __restrict__ cnt_src,
                                             float* __restrict__ partial) {
    __shared__ float nlds[64][37];
    __shared__ float pk[4][64][36];
    __shared__ float pv[4][64][36];
    const int tid = threadIdx.x;
    const int w_u = __builtin_amdgcn_readfirstlane(tid >> 6);
    const int m_u = w_u >> 2;      // 0 = k, 1 = v
    const int h_u = w_u & 3;
    const int lane = tid & 63;
    const float inv = 1.f / fabsf(nscale[0]);
    const float* W = ((m_u == 0) ? Wk : Wv) + (size_t)h_u * 33 * 32;
    const float* bb = ((m_u == 0) ? bk : bv) + h_u * 32;
    const int mm4 = lane >> 3, d4 = lane & 7;

    float facc[16];
#pragma unroll
    for (int t = 0; t < 16; ++t) facc[t] = 0.f;
    float ks[4] = {0.f, 0.f, 0.f, 0.f};

    const int ntiles = (NN + 63) / 64;
    for (int tile = blockIdx.x; tile < ntiles; tile += QKV_BLOCKS) {
        const int base = tile * 64;
        const int n = base + lane;
        // stage node vectors [64][33] from column-major global
#pragma unroll
        for (int r = 0; r < 5; ++r) {
            int idx = r * 512 + tid;
            if (idx < 2112) {
                int c = idx >> 6, sn = idx & 63;
                int gn = base + sn;
                nlds[sn][c] = node33T[(size_t)c * NN + ((gn < NN) ? gn : 0)];
            }
        }
        __syncthreads();

        float acc[32];
#pragma unroll
        for (int j = 0; j < 32; ++j) acc[j] = bb[j];
        for (int i = 0; i < 33; ++i) {
            float hv = nlds[lane][i];
            const float* wr = W + (size_t)i * 32;
#pragma unroll
            for (int j = 0; j < 32; ++j) acc[j] = fmaf(hv, wr[j], acc[j]);
        }

        if (m_u == 0) {
            const float wc = (n < NN) ? (float)cnt_src[n] : 0.f;
            float s2 = 0.f, s6 = 0.f;
#pragma unroll
            for (int j = 0; j < 32; ++j) {
                float x = (lrelu(acc[j]) + 1e-6f) * inv;
                s2 += x * x;
                float x3 = x * x * x;
                s6 += x3 * x3;
                acc[j] = x3;
            }
            const float factor = sqrtf(s2) / sqrtf(s6) * wc;
#pragma unroll
            for (int j = 0; j < 32; ++j) pk[h_u][lane][j] = factor * acc[j];
        } else {
#pragma unroll
            for (int j = 0; j < 32; ++j) pv[h_u][lane][j] = (lrelu(acc[j]) + 1e-6f) * inv;
        }
        __syncthreads();

        // ktv accumulate: k-waves take nodes 0..31, v-waves take 32..63 (head h_u).
#pragma unroll 4
        for (int n0 = 0; n0 < 32; ++n0) {
            const int nn = m_u * 32 + n0;
            float4 pkv = *(const float4*)&pk[h_u][nn][mm4 * 4];
            float4 pvv = *(const float4*)&pv[h_u][nn][d4 * 4];
            float pkv_a[4] = {pkv.x, pkv.y, pkv.z, pkv.w};
            float pvv_a[4] = {pvv.x, pvv.y, pvv.z, pvv.w};
#pragma unroll
            for (int i = 0; i < 4; ++i)
#pragma unroll
                for (int jj = 0; jj < 4; ++jj)
                    facc[i * 4 + jj] = fmaf(pkv_a[i], pvv_a[jj], facc[i * 4 + jj]);
            if (d4 == 0) {
#pragma unroll
                for (int i = 0; i < 4; ++i) ks[i] += pkv_a[i];
            }
        }
        // next iteration's nlds staging is safe (ktv doesn't read nlds);
        // pk/pv overwrite is fenced by the post-staging __syncthreads.
    }

    float* pb = partial + (size_t)(blockIdx.x * 2 + m_u) * KTVC;
#pragma unroll
    for (int i = 0; i < 4; ++i)
#pragma unroll
        for (int jj = 0; jj < 4; ++jj)
            pb[h_u * 1024 + (mm4 * 4 + i) * 32 + d4 * 4 + jj] = facc[i * 4 + jj];
    if (d4 == 0) {
#pragma unroll
        for (int i = 0; i < 4; ++i) pb[4096 + h_u * 32 + mm4 * 4 + i] = ks[i];
    }
}

// ---------------- kernel 4: parallel reduce of 512 partial rows ----------------
// 132 blocks x 256 threads; block owns 32 columns, 8 row-groups of 64 rows.
__global__ __launch_bounds__(256) void k_red(const float* __restrict__ partial,
                                             float* __restrict__ ktvf) {
    __shared__ float red[8][33];
    const int tid = threadIdx.x;
    const int col = tid & 31, g = tid >> 5;
    const int c = blockIdx.x * 32 + col;
    float s = 0.f;
    for (int r = g * 64; r < (g + 1) * 64; ++r)
        s += partial[(size_t)r * KTVC + c];
    red[g][col] = s;
    __syncthreads();
    if (tid < 32) {
        float t0 = (red[0][tid] + red[1][tid]) + (red[2][tid] + red[3][tid]);
        float t1 = (red[4][tid] + red[5][tid]) + (red[6][tid] + red[7][tid]);
        ktvf[blockIdx.x * 32 + tid] = t0 + t1;
    }
}

// ---------------- kernel 5: q + phi_q + attention + edge_out + midpoint + LN2 ----------------
// 256 threads = 4 waves (one head each) x 64 nodes.
__global__ __launch_bounds__(256) void k_final(const float* __restrict__ node33T,
                                               const float* __restrict__ Wq, const float* __restrict__ bq,
                                               const float* __restrict__ nscale,
                                               const float* __restrict__ ktvf,
                                               const float* __restrict__ Who,
                                               const float* __restrict__ bho,
                                               const float* __restrict__ g2,
                                               const float* __restrict__ b2,
                                               const int* __restrict__ cnt_dst,
                                               const float* __restrict__ resid,
                                               float* __restrict__ out) {
    __shared__ float nlds[64][37];
    __shared__ float att[4][64][33];
    __shared__ float who_lds[33 * 32];
    __shared__ float g2l[32], b2l[32], bhol[32];
    const int tid = threadIdx.x;
    const int h_u = __builtin_amdgcn_readfirstlane(tid >> 6);
    const int lane = tid & 63;
    const int base = blockIdx.x * 64;
    const float inv = 1.f / fabsf(nscale[0]);

#pragma unroll
    for (int r = 0; r < 9; ++r) {
        int idx = r * 256 + tid;
        if (idx < 2112) {
            int c = idx >> 6, sn = idx & 63;
            int gn = base + sn;
            nlds[sn][c] = node33T[(size_t)c * NN + ((gn < NN) ? gn : 0)];
        }
    }
    for (int f = tid; f < 33 * 32; f += 256) who_lds[f] = Who[f];
    if (tid < 32) { g2l[tid] = g2[tid]; b2l[tid] = b2[tid]; bhol[tid] = bho[tid]; }
    __syncthreads();

    // ---- phase A: per (node, head): q matvec + phi_q + num/den ----
    {
        float acc[32];
#pragma unroll
        for (int j = 0; j < 32; ++j) acc[j] = bq[h_u * 32 + j];
        const float* W = Wq + (size_t)h_u * 33 * 32;
        for (int i = 0; i < 33; ++i) {
            float hv = nlds[lane][i];
            const float* wr = W + (size_t)i * 32;
#pragma unroll
            for (int j = 0; j < 32; ++j) acc[j] = fmaf(hv, wr[j], acc[j]);
        }
        float s2 = 0.f, s6 = 0.f;
#pragma unroll
        for (int j = 0; j < 32; ++j) {
            float x = (lrelu(acc[j]) + 1e-6f) * inv;
            s2 += x * x;
            float x3 = x * x * x;
            s6 += x3 * x3;
            acc[j] = x3;
        }
        const float factor = sqrtf(s2) / sqrtf(s6);
        const float* ksum = ktvf + 4096 + h_u * 32;
        float den = 0.f;
#pragma unroll
        for (int j = 0; j < 32; ++j) { acc[j] *= factor; den += acc[j] * ksum[j]; }
        const float rd = 0.25f / (den + 1e-6f);
        float num[32];
#pragma unroll
        for (int d = 0; d < 32; ++d) num[d] = 0.f;
        const float* kt = ktvf + h_u * 1024;
#pragma unroll 2
        for (int t = 0; t < 32; ++t) {
            const float f = acc[t];
            const float* kr = kt + t * 32;
#pragma unroll
            for (int d = 0; d < 32; ++d) num[d] = fmaf(f, kr[d], num[d]);
        }
#pragma unroll
        for (int d = 0; d < 32; ++d) att[h_u][lane][d] = num[d] * rd;
    }
    __syncthreads();

    // ---- phase B: per node (4 threads each, jq = quarter of output cols) ----
    const int nl2 = tid >> 2, jq = tid & 3;
    const int n2 = base + nl2;
    const int nc = (n2 < NN) ? n2 : NN - 1;
    float attn[32];
#pragma unroll
    for (int d = 0; d < 32; ++d)
        attn[d] = ((att[0][nl2][d] + att[1][nl2][d]) + (att[2][nl2][d] + att[3][nl2][d]));
    float a2 = 0.f;
#pragma unroll
    for (int d = 0; d < 32; ++d) a2 += attn[d] * attn[d];
    const float tc = sqrtf(a2 + 1.f);
    float eo[8];
#pragma unroll
    for (int jj = 0; jj < 8; ++jj) {
        int j = jq * 8 + jj;
        eo[jj] = bhol[j] + tc * who_lds[j];
    }
#pragma unroll
    for (int d = 0; d < 32; ++d) {
        const float f = attn[d];
        const float* wr = &who_lds[(1 + d) * 32 + jq * 8];
#pragma unroll
        for (int jj = 0; jj < 8; ++jj) eo[jj] = fmaf(f, wr[jj], eo[jj]);
    }
    float e2 = 0.f;
#pragma unroll
    for (int jj = 0; jj < 8; ++jj) e2 += eo[jj] * eo[jj];
    e2 += __shfl_xor(e2, 1);
    e2 += __shfl_xor(e2, 2);
    const float te = sqrtf(e2 + 1.f);
    const float sc = (cnt_dst[nc] > 0) ? 1.f : 0.f;
    const float* rr = resid + (size_t)nc * 36;
    const float av0 = 0.5f * (sc * te + rr[0]);
    float avs[8];
    float pinner = 0.f;
#pragma unroll
    for (int jj = 0; jj < 8; ++jj) {
        avs[jj] = 0.5f * (sc * eo[jj] + rr[1 + jq * 8 + jj]);
        pinner += avs[jj] * avs[jj];
    }
    pinner += __shfl_xor(pinner, 1);
    pinner += __shfl_xor(pinner, 2);
    const float inner = pinner - av0 * av0;
    const float rdn = 1.f / sqrtf(fmaxf(fabsf(inner), 1e-6f));
    float pm = 0.f;
#pragma unroll
    for (int jj = 0; jj < 8; ++jj) { avs[jj] *= rdn; pm += avs[jj]; }
    pm += __shfl_xor(pm, 1);
    pm += __shfl_xor(pm, 2);
    const float mean = pm * (1.f / 32.f);
    float pv2 = 0.f;
#pragma unroll
    for (int jj = 0; jj < 8; ++jj) { float dd = avs[jj] - mean; pv2 += dd * dd; }
    pv2 += __shfl_xor(pv2, 1);
    pv2 += __shfl_xor(pv2, 2);
    const float rstd = rsqrtf(pv2 * (1.f / 32.f) + 1e-5f);
    float ln[8];
    float pl2 = 0.f;
#pragma unroll
    for (int jj = 0; jj < 8; ++jj) {
        int j = jq * 8 + jj;
        ln[jj] = (avs[jj] - mean) * rstd * g2l[j] + b2l[j];
        pl2 += ln[jj] * ln[jj];
    }
    pl2 += __shfl_xor(pl2, 1);
    pl2 += __shfl_xor(pl2, 2);
    if (n2 < NN) {
        float* orow = out + (size_t)n2 * 33;
#pragma unroll
        for (int jj = 0; jj < 8; ++jj) orow[1 + jq * 8 + jj] = ln[jj];
        if (jq == 0) orow[0] = sqrtf(pl2 + 1.f);
    }
}

extern "C" void kernel_launch(void* const* d_in, const int* in_sizes, int n_in,
                              void* d_out, int out_size, void* d_ws, size_t ws_size,
                              hipStream_t stream) {
    const float* h   = (const float*)d_in[0];
    const int* src   = (const int*)d_in[1];
    const int* dst   = (const int*)d_in[2];
    const float* Wfc = (const float*)d_in[3];
    const float* bfc = (const float*)d_in[4];
    const float* g1  = (const float*)d_in[5];
    const float* b1  = (const float*)d_in[6];
    const float* Wq  = (const float*)d_in[7];
    const float* bq  = (const float*)d_in[8];
    const float* Wk  = (const float*)d_in[9];
    const float* bk  = (const float*)d_in[10];
    const float* Wv  = (const float*)d_in[11];
    const float* bv  = (const float*)d_in[12];
    const float* Who = (const float*)d_in[13];
    const float* bho = (const float*)d_in[14];
    const float* g2  = (const float*)d_in[15];
    const float* b2  = (const float*)d_in[16];
    const float* nsc = (const float*)d_in[17];
    float* out = (float*)d_out;
    char* ws = (char*)d_ws;

    int* cnt_src   = (int*)(ws + 0);           //  200,000 B
    int* cnt_dst   = (int*)(ws + 200000);      //  200,000 B
    float* resid   = (float*)(ws + 400000);    //  7.2 MB  [NN][36]
    float* node33T = (float*)(ws + 7600000);   //  6.6 MB  [33][NN]
    float* part    = (float*)(ws + 14200000);  //  8.65 MB [512][4224]
    float* ktvf    = (float*)(ws + 22852608);  //  16.9 KB

    hipMemsetAsync(ws, 0, 400000, stream);
    hipLaunchKernelGGL(k_hist, dim3((NE + 255) / 256), dim3(256), 0, stream,
                       src, dst, cnt_src, cnt_dst);
    hipLaunchKernelGGL(k_fc, dim3((NN + 127) / 128), dim3(512), 0, stream,
                       h, Wfc, bfc, g1, b1, resid, node33T);
    hipLaunchKernelGGL(k_qkv, dim3(QKV_BLOCKS), dim3(512), 0, stream,
                       node33T, Wk, bk, Wv, bv, nsc, cnt_src, part);
    hipLaunchKernelGGL(k_red, dim3(KTVC / 32), dim3(256), 0, stream,
                       part, ktvf);
    hipLaunchKernelGGL(k_final, dim3((NN + 63) / 64), dim3(256), 0, stream,
                       node33T, Wq, bq, nsc, ktvf, Who, bho, g2, b2, cnt_dst, resid, out);
}

// Round 4
// 126.854 us; speedup vs baseline: 1.7395x; 1.1361x over previous
//
#include <hip/hip_runtime.h>

#define NN 50000
#define NE 250000
#define KTVC 4224        // 4 heads x (1024 ktv + 32 ksum)
#define NBX 512          // tile-stride blocks per head for k_qkv

__device__ __forceinline__ float lrelu(float x) { return x > 0.f ? x : 0.01f * x; }

// ---------------- kernel 1: histograms ----------------
__global__ __launch_bounds__(256) void k_hist(const int* __restrict__ src,
                                              const int* __restrict__ dst,
                                              int* __restrict__ cnt_src,
                                              int* __restrict__ cnt_dst) {
    int e = blockIdx.x * 256 + threadIdx.x;
    if (e < NE) {
        atomicAdd(&cnt_src[src[e]], 1);
        atomicAdd(&cnt_dst[dst[e]], 1);
    }
}

// ---------------- kernel 2: fc + LN + leaky ----------------
// 512 threads = 4 col-quarters x 128 nodes. lane-per-node, scalar weights.
__global__ __launch_bounds__(512) void k_fc(const float* __restrict__ h,
                                            const float* __restrict__ Wfc,
                                            const float* __restrict__ bfc,
                                            const float* __restrict__ g1,
                                            const float* __restrict__ b1,
                                            float* __restrict__ resid,
                                            float* __restrict__ node33T) {
    __shared__ float hch[128][33];
    __shared__ float stat_t[8][128];
    __shared__ float stat2_t[4][128];
    const int tid = threadIdx.x;
    const int q = __builtin_amdgcn_readfirstlane((threadIdx.x >> 7) & 3);
    const int nl = tid & 127;
    const int base = blockIdx.x * 128;
    const int n = base + nl;

    float acc[8];
#pragma unroll
    for (int jj = 0; jj < 8; ++jj) acc[jj] = Wfc[q * 8 + jj] + bfc[q * 8 + jj];

    for (int c = 0; c < 4; ++c) {
        __syncthreads();
#pragma unroll
        for (int r = 0; r < 8; ++r) {
            int idx = r * 512 + tid;
            int sn = idx >> 5, t = idx & 31;
            int gn = base + sn;
            hch[sn][t] = h[(size_t)((gn < NN) ? gn : 0) * 128 + c * 32 + t];
        }
        __syncthreads();
        for (int i = 0; i < 32; ++i) {
            float hv = hch[nl][i];
            const float* wr = Wfc + (size_t)(1 + c * 32 + i) * 32 + q * 8;
#pragma unroll
            for (int jj = 0; jj < 8; ++jj) acc[jj] = fmaf(hv, wr[jj], acc[jj]);
        }
    }
    float ps = 0.f, pq2 = 0.f;
#pragma unroll
    for (int jj = 0; jj < 8; ++jj) { ps += acc[jj]; pq2 += acc[jj] * acc[jj]; }
    stat_t[q * 2 + 0][nl] = ps;
    stat_t[q * 2 + 1][nl] = pq2;
    __syncthreads();
    float sm = stat_t[0][nl] + stat_t[2][nl] + stat_t[4][nl] + stat_t[6][nl];
    float sq = stat_t[1][nl] + stat_t[3][nl] + stat_t[5][nl] + stat_t[7][nl];
    float mean = sm * (1.f / 32.f);
    float var = fmaxf(sq * (1.f / 32.f) - mean * mean, 0.f);
    float rstd = rsqrtf(var + 1e-5f);
    float lr[8];
    float pl2 = 0.f;
#pragma unroll
    for (int jj = 0; jj < 8; ++jj) {
        int j = q * 8 + jj;
        float ln = (acc[jj] - mean) * rstd * g1[j] + b1[j];
        lr[jj] = lrelu(ln);
        pl2 += lr[jj] * lr[jj];
    }
    stat2_t[q][nl] = pl2;
    __syncthreads();
    float l2 = stat2_t[0][nl] + stat2_t[1][nl] + stat2_t[2][nl] + stat2_t[3][nl];
    if (n < NN) {
        float* rrow = resid + (size_t)n * 36;
#pragma unroll
        for (int jj = 0; jj < 8; ++jj) rrow[1 + q * 8 + jj] = acc[jj];
#pragma unroll
        for (int jj = 0; jj < 8; ++jj) node33T[(size_t)(1 + q * 8 + jj) * NN + n] = lr[jj];
        if (q == 0) {
            rrow[0] = sqrtf(sq + 1.f);
            node33T[n] = sqrtf(l2 + 1.f);
        }
    }
}

// ---------------- kernel 3: per-head k/v matvec + phi + register ktv partials ----------------
// grid (NBX, 4 heads); block 128 = wave0 (k) + wave1 (v); lanes = 64 nodes of tile.
__global__ __launch_bounds__(128) void k_qkv(const float* __restrict__ node33T,
                                             const float* __restrict__ Wk, const float* __restrict__ bk,
                                             const float* __restrict__ Wv, const float* __restrict__ bv,
                                             const float* __restrict__ nscale,
                                             const int* __restrict__ cnt_src,
                                             float* __restrict__ partial) {
    __shared__ float nlds[64][33];
    __shared__ float pk[64][36];
    __shared__ float pv[64][36];
    const int tid = threadIdx.x;
    const int w_u = __builtin_amdgcn_readfirstlane(tid >> 6);   // 0 = k, 1 = v
    const int h_u = __builtin_amdgcn_readfirstlane(blockIdx.y);
    const int lane = tid & 63;
    const float inv = 1.f / fabsf(nscale[0]);
    const float* W = ((w_u == 0) ? Wk : Wv) + (size_t)h_u * 33 * 32;
    const float* bb = ((w_u == 0) ? bk : bv) + h_u * 32;
    const int mm4 = lane >> 3, d4 = lane & 7;

    float facc[16];
#pragma unroll
    for (int t = 0; t < 16; ++t) facc[t] = 0.f;
    float ks[4] = {0.f, 0.f, 0.f, 0.f};

    const int ntiles = (NN + 63) / 64;
    for (int tile = blockIdx.x; tile < ntiles; tile += NBX) {
        const int base = tile * 64;
        const int n = base + lane;
        // stage node vectors [64][33] from column-major global (coalesced per column)
        for (int idx = tid; idx < 2112; idx += 128) {
            int c = idx >> 6, sn = idx & 63;
            int gn = base + sn;
            nlds[sn][c] = node33T[(size_t)c * NN + ((gn < NN) ? gn : 0)];
        }
        __syncthreads();

        float acc[32];
#pragma unroll
        for (int j = 0; j < 32; ++j) acc[j] = bb[j];
        for (int i = 0; i < 33; ++i) {
            float hv = nlds[lane][i];
            const float* wr = W + (size_t)i * 32;
#pragma unroll
            for (int j = 0; j < 32; ++j) acc[j] = fmaf(hv, wr[j], acc[j]);
        }

        if (w_u == 0) {
            const float wc = (n < NN) ? (float)cnt_src[n] : 0.f;
            float s2 = 0.f, s6 = 0.f;
#pragma unroll
            for (int j = 0; j < 32; ++j) {
                float x = (lrelu(acc[j]) + 1e-6f) * inv;
                s2 += x * x;
                float x3 = x * x * x;
                s6 += x3 * x3;
                acc[j] = x3;
            }
            const float factor = sqrtf(s2) / sqrtf(s6) * wc;
#pragma unroll
            for (int j = 0; j < 32; ++j) pk[lane][j] = factor * acc[j];
        } else {
#pragma unroll
            for (int j = 0; j < 32; ++j) pv[lane][j] = (lrelu(acc[j]) + 1e-6f) * inv;
        }
        __syncthreads();

        // ktv accumulate: wave0 nodes 0..31, wave1 nodes 32..63.
#pragma unroll 4
        for (int n0 = 0; n0 < 32; ++n0) {
            const int nn = w_u * 32 + n0;
            float4 pkv = *(const float4*)&pk[nn][mm4 * 4];
            float4 pvv = *(const float4*)&pv[nn][d4 * 4];
            float pkv_a[4] = {pkv.x, pkv.y, pkv.z, pkv.w};
            float pvv_a[4] = {pvv.x, pvv.y, pvv.z, pvv.w};
#pragma unroll
            for (int i = 0; i < 4; ++i)
#pragma unroll
                for (int jj = 0; jj < 4; ++jj)
                    facc[i * 4 + jj] = fmaf(pkv_a[i], pvv_a[jj], facc[i * 4 + jj]);
            if (d4 == 0) {
#pragma unroll
                for (int i = 0; i < 4; ++i) ks[i] += pkv_a[i];
            }
        }
        __syncthreads();   // pk/pv reads done before next tile's overwrite
    }

    // merge the two waves' partials through LDS scratch (pk/pv are dead now)
    float* scr = &pk[0][0];      // 1024 floats
    float* scr2 = &pv[0][0];     // 32 floats
    if (w_u == 0) {
#pragma unroll
        for (int t = 0; t < 16; ++t) scr[lane * 16 + t] = facc[t];
        if (d4 == 0) {
#pragma unroll
            for (int i = 0; i < 4; ++i) scr2[mm4 * 4 + i] = ks[i];
        }
    }
    __syncthreads();
    if (w_u == 1) {
        float* pb = partial + (size_t)blockIdx.x * KTVC + h_u * 1056;
#pragma unroll
        for (int i = 0; i < 4; ++i)
#pragma unroll
            for (int jj = 0; jj < 4; ++jj)
                pb[(mm4 * 4 + i) * 32 + d4 * 4 + jj] =
                    facc[i * 4 + jj] + scr[lane * 16 + i * 4 + jj];
        if (d4 == 0) {
#pragma unroll
            for (int i = 0; i < 4; ++i)
                pb[1024 + mm4 * 4 + i] = ks[i] + scr2[mm4 * 4 + i];
        }
    }
}

// ---------------- kernel 4: parallel reduce of 512 partial rows ----------------
__global__ __launch_bounds__(256) void k_red(const float* __restrict__ partial,
                                             float* __restrict__ ktvf) {
    __shared__ float red[8][33];
    const int tid = threadIdx.x;
    const int col = tid & 31, g = tid >> 5;
    const int c = blockIdx.x * 32 + col;
    float s = 0.f;
    for (int r = g * 64; r < (g + 1) * 64; ++r)
        s += partial[(size_t)r * KTVC + c];
    red[g][col] = s;
    __syncthreads();
    if (tid < 32) {
        float t0 = (red[0][tid] + red[1][tid]) + (red[2][tid] + red[3][tid]);
        float t1 = (red[4][tid] + red[5][tid]) + (red[6][tid] + red[7][tid]);
        ktvf[blockIdx.x * 32 + tid] = t0 + t1;
    }
}

// ---------------- kernel 5: q + phi_q + attention + edge_out + midpoint + LN2 ----------------
// 256 threads = 4 waves (one head each) x 64 nodes.
__global__ __launch_bounds__(256) void k_final(const float* __restrict__ node33T,
                                               const float* __restrict__ Wq, const float* __restrict__ bq,
                                               const float* __restrict__ nscale,
                                               const float* __restrict__ ktvf,
                                               const float* __restrict__ Who,
                                               const float* __restrict__ bho,
                                               const float* __restrict__ g2,
                                               const float* __restrict__ b2,
                                               const int* __restrict__ cnt_dst,
                                               const float* __restrict__ resid,
                                               float* __restrict__ out) {
    __shared__ float nlds[64][37];
    __shared__ float att[4][64][33];
    __shared__ float who_lds[33 * 32];
    __shared__ float g2l[32], b2l[32], bhol[32];
    const int tid = threadIdx.x;
    const int h_u = __builtin_amdgcn_readfirstlane(tid >> 6);
    const int lane = tid & 63;
    const int base = blockIdx.x * 64;
    const float inv = 1.f / fabsf(nscale[0]);

#pragma unroll
    for (int r = 0; r < 9; ++r) {
        int idx = r * 256 + tid;
        if (idx < 2112) {
            int c = idx >> 6, sn = idx & 63;
            int gn = base + sn;
            nlds[sn][c] = node33T[(size_t)c * NN + ((gn < NN) ? gn : 0)];
        }
    }
    for (int f = tid; f < 33 * 32; f += 256) who_lds[f] = Who[f];
    if (tid < 32) { g2l[tid] = g2[tid]; b2l[tid] = b2[tid]; bhol[tid] = bho[tid]; }
    __syncthreads();

    // ---- phase A: per (node, head): q matvec + phi_q + num/den ----
    {
        float acc[32];
#pragma unroll
        for (int j = 0; j < 32; ++j) acc[j] = bq[h_u * 32 + j];
        const float* W = Wq + (size_t)h_u * 33 * 32;
        for (int i = 0; i < 33; ++i) {
            float hv = nlds[lane][i];
            const float* wr = W + (size_t)i * 32;
#pragma unroll
            for (int j = 0; j < 32; ++j) acc[j] = fmaf(hv, wr[j], acc[j]);
        }
        float s2 = 0.f, s6 = 0.f;
#pragma unroll
        for (int j = 0; j < 32; ++j) {
            float x = (lrelu(acc[j]) + 1e-6f) * inv;
            s2 += x * x;
            float x3 = x * x * x;
            s6 += x3 * x3;
            acc[j] = x3;
        }
        const float factor = sqrtf(s2) / sqrtf(s6);
        const float* ksum = ktvf + h_u * 1056 + 1024;
        float den = 0.f;
#pragma unroll
        for (int j = 0; j < 32; ++j) { acc[j] *= factor; den += acc[j] * ksum[j]; }
        const float rd = 0.25f / (den + 1e-6f);
        float num[32];
#pragma unroll
        for (int d = 0; d < 32; ++d) num[d] = 0.f;
        const float* kt = ktvf + h_u * 1056;
#pragma unroll 2
        for (int t = 0; t < 32; ++t) {
            const float f = acc[t];
            const float* kr = kt + t * 32;
#pragma unroll
            for (int d = 0; d < 32; ++d) num[d] = fmaf(f, kr[d], num[d]);
        }
#pragma unroll
        for (int d = 0; d < 32; ++d) att[h_u][lane][d] = num[d] * rd;
    }
    __syncthreads();

    // ---- phase B: per node (4 threads each, jq = quarter of output cols) ----
    const int nl2 = tid >> 2, jq = tid & 3;
    const int n2 = base + nl2;
    const int nc = (n2 < NN) ? n2 : NN - 1;
    float attn[32];
#pragma unroll
    for (int d = 0; d < 32; ++d)
        attn[d] = ((att[0][nl2][d] + att[1][nl2][d]) + (att[2][nl2][d] + att[3][nl2][d]));
    float a2 = 0.f;
#pragma unroll
    for (int d = 0; d < 32; ++d) a2 += attn[d] * attn[d];
    const float tc = sqrtf(a2 + 1.f);
    float eo[8];
#pragma unroll
    for (int jj = 0; jj < 8; ++jj) {
        int j = jq * 8 + jj;
        eo[jj] = bhol[j] + tc * who_lds[j];
    }
#pragma unroll
    for (int d = 0; d < 32; ++d) {
        const float f = attn[d];
        const float* wr = &who_lds[(1 + d) * 32 + jq * 8];
#pragma unroll
        for (int jj = 0; jj < 8; ++jj) eo[jj] = fmaf(f, wr[jj], eo[jj]);
    }
    float e2 = 0.f;
#pragma unroll
    for (int jj = 0; jj < 8; ++jj) e2 += eo[jj] * eo[jj];
    e2 += __shfl_xor(e2, 1);
    e2 += __shfl_xor(e2, 2);
    const float te = sqrtf(e2 + 1.f);
    const float sc = (cnt_dst[nc] > 0) ? 1.f : 0.f;
    const float* rr = resid + (size_t)nc * 36;
    const float av0 = 0.5f * (sc * te + rr[0]);
    float avs[8];
    float pinner = 0.f;
#pragma unroll
    for (int jj = 0; jj < 8; ++jj) {
        avs[jj] = 0.5f * (sc * eo[jj] + rr[1 + jq * 8 + jj]);
        pinner += avs[jj] * avs[jj];
    }
    pinner += __shfl_xor(pinner, 1);
    pinner += __shfl_xor(pinner, 2);
    const float inner = pinner - av0 * av0;
    const float rdn = 1.f / sqrtf(fmaxf(fabsf(inner), 1e-6f));
    float pm = 0.f;
#pragma unroll
    for (int jj = 0; jj < 8; ++jj) { avs[jj] *= rdn; pm += avs[jj]; }
    pm += __shfl_xor(pm, 1);
    pm += __shfl_xor(pm, 2);
    const float mean = pm * (1.f / 32.f);
    float pv2 = 0.f;
#pragma unroll
    for (int jj = 0; jj < 8; ++jj) { float dd = avs[jj] - mean; pv2 += dd * dd; }
    pv2 += __shfl_xor(pv2, 1);
    pv2 += __shfl_xor(pv2, 2);
    const float rstd = rsqrtf(pv2 * (1.f / 32.f) + 1e-5f);
    float ln[8];
    float pl2 = 0.f;
#pragma unroll
    for (int jj = 0; jj < 8; ++jj) {
        int j = jq * 8 + jj;
        ln[jj] = (avs[jj] - mean) * rstd * g2l[j] + b2l[j];
        pl2 += ln[jj] * ln[jj];
    }
    pl2 += __shfl_xor(pl2, 1);
    pl2 += __shfl_xor(pl2, 2);
    if (n2 < NN) {
        float* orow = out + (size_t)n2 * 33;
#pragma unroll
        for (int jj = 0; jj < 8; ++jj) orow[1 + jq * 8 + jj] = ln[jj];
        if (jq == 0) orow[0] = sqrtf(pl2 + 1.f);
    }
}

extern "C" void kernel_launch(void* const* d_in, const int* in_sizes, int n_in,
                              void* d_out, int out_size, void* d_ws, size_t ws_size,
                              hipStream_t stream) {
    const float* h   = (const float*)d_in[0];
    const int* src   = (const int*)d_in[1];
    const int* dst   = (const int*)d_in[2];
    const float* Wfc = (const float*)d_in[3];
    const float* bfc = (const float*)d_in[4];
    const float* g1  = (const float*)d_in[5];
    const float* b1  = (const float*)d_in[6];
    const float* Wq  = (const float*)d_in[7];
    const float* bq  = (const float*)d_in[8];
    const float* Wk  = (const float*)d_in[9];
    const float* bk  = (const float*)d_in[10];
    const float* Wv  = (const float*)d_in[11];
    const float* bv  = (const float*)d_in[12];
    const float* Who = (const float*)d_in[13];
    const float* bho = (const float*)d_in[14];
    const float* g2  = (const float*)d_in[15];
    const float* b2  = (const float*)d_in[16];
    const float* nsc = (const float*)d_in[17];
    float* out = (float*)d_out;
    char* ws = (char*)d_ws;

    int* cnt_src   = (int*)(ws + 0);           //  200,000 B
    int* cnt_dst   = (int*)(ws + 200000);      //  200,000 B
    float* resid   = (float*)(ws + 400000);    //  7.2 MB  [NN][36]
    float* node33T = (float*)(ws + 7600000);   //  6.6 MB  [33][NN]
    float* part    = (float*)(ws + 14200000);  //  8.65 MB [512][4224]
    float* ktvf    = (float*)(ws + 22852608);  //  16.9 KB

    hipMemsetAsync(ws, 0, 400000, stream);
    hipLaunchKernelGGL(k_hist, dim3((NE + 255) / 256), dim3(256), 0, stream,
                       src, dst, cnt_src, cnt_dst);
    hipLaunchKernelGGL(k_fc, dim3((NN + 127) / 128), dim3(512), 0, stream,
                       h, Wfc, bfc, g1, b1, resid, node33T);
    hipLaunchKernelGGL(k_qkv, dim3(NBX, 4), dim3(128), 0, stream,
                       node33T, Wk, bk, Wv, bv, nsc, cnt_src, part);
    hipLaunchKernelGGL(k_red, dim3(KTVC / 32), dim3(256), 0, stream,
                       part, ktvf);
    hipLaunchKernelGGL(k_final, dim3((NN + 63) / 64), dim3(256), 0, stream,
                       node33T, Wq, bq, nsc, ktvf, Who, bho, g2, b2, cnt_dst, resid, out);
}